// Round 3
// baseline (200.579 us; speedup 1.0000x reference)
//
#include <hip/hip_runtime.h>
#include <hip/hip_bf16.h>
#include <math.h>

#define Bn 4
#define Cn 64
#define Pn 4096   // 64*64
#define QT 32     // q-tile per block
#define PBK 128   // p-block per flash iteration
#define LOG2E 1.4426950408889634f

typedef __attribute__((ext_vector_type(8))) short short8;   // 8 bf16 = 4 VGPRs (MFMA A/B frag)
typedef __attribute__((ext_vector_type(4))) float float4v;  // MFMA C/D frag
typedef unsigned short bfu;

__device__ __forceinline__ bfu f2bf(float x) {
    unsigned u = __float_as_uint(x);
    u = (u + 0x7fffu + ((u >> 16) & 1u)) >> 16;   // RNE; inputs finite
    return (bfu)u;
}

// ---------------------------------------------------------------------------
// Prep (fused): blocks [0,256): L2-normalize K -> bf16 Kpc [B][P][C] + Kcp [B][C][P]
//               blocks [256,512): 3x3 zero-padded box-sum * log2(e) -> S [B][C][P]
// ---------------------------------------------------------------------------
__global__ __launch_bounds__(256) void prep_kernel(const float* __restrict__ fg,
                                                   bfu* __restrict__ Kpc,
                                                   bfu* __restrict__ Kcp,
                                                   float* __restrict__ S) {
    __shared__ float shbuf[64 * 65 + 64];
    int t = threadIdx.x;
    if (blockIdx.x < 256) {
        float (*tile)[65] = (float(*)[65])shbuf;
        float* rnorm = shbuf + 64 * 65;
        int b  = blockIdx.x >> 6;
        int p0 = (blockIdx.x & 63) << 6;
        const float* src = fg + (size_t)b * Cn * Pn + p0;
        int lp = t & 63, lg = t >> 6;
        #pragma unroll
        for (int i = 0; i < 16; ++i) {
            int c = i * 4 + lg;
            tile[c][lp] = src[(size_t)c * Pn + lp];   // coalesced over p
        }
        __syncthreads();
        if (t < 64) {
            float ss = 0.f;
            #pragma unroll
            for (int c = 0; c < 64; ++c) { float v = tile[c][t]; ss += v * v; }
            rnorm[t] = 1.0f / (sqrtf(ss) + 1e-8f);
        }
        __syncthreads();
        bfu* dpc = Kpc + (size_t)b * Pn * Cn + (size_t)p0 * Cn;
        int oc = t & 63, og = t >> 6;
        #pragma unroll
        for (int i = 0; i < 16; ++i) {
            int p = i * 4 + og;
            dpc[(size_t)p * Cn + oc] = f2bf(tile[oc][p] * rnorm[p]);  // coalesced over c
        }
        bfu* dcp = Kcp + (size_t)b * Cn * Pn + p0;
        #pragma unroll
        for (int i = 0; i < 16; ++i) {
            int c = i * 4 + lg;
            dcp[(size_t)c * Pn + lp] = f2bf(tile[c][lp] * rnorm[lp]); // coalesced over p
        }
    } else {
        float (*pl)[64] = (float(*)[64])shbuf;
        int bc = blockIdx.x - 256;
        const float* src = fg + (size_t)bc * Pn;
        float*       dst = S  + (size_t)bc * Pn;
        #pragma unroll
        for (int i = 0; i < 16; ++i) {
            int idx = i * 256 + t;
            pl[idx >> 6][idx & 63] = src[idx];
        }
        __syncthreads();
        #pragma unroll
        for (int i = 0; i < 16; ++i) {
            int idx = i * 256 + t;
            int h = idx >> 6, w = idx & 63;
            float s = 0.f;
            #pragma unroll
            for (int dh = -1; dh <= 1; ++dh) {
                int hh = h + dh;
                if (hh < 0 || hh >= 64) continue;
                #pragma unroll
                for (int dw = -1; dw <= 1; ++dw) {
                    int ww = w + dw;
                    if (ww < 0 || ww >= 64) continue;
                    s += pl[hh][ww];
                }
            }
            dst[idx] = s * LOG2E;   // pre-scale so flash uses exp2 directly
        }
    }
}

// ---------------------------------------------------------------------------
// Flash (no-max softmax; scores bounded: |s*log2e| <~ 50, exp2 safe in fp32/bf16):
//   out[:,q] = K^T exp2(K·S'_q) / l_q ,  l accumulated per-lane in registers.
// grid = B * 128 (QT=32); 256 threads = 4 waves; p streamed in blocks of 128.
// All LDS tiles XOR-swizzled on 16B chunks (conflict-free, no padding).
// ---------------------------------------------------------------------------
__global__ __launch_bounds__(256, 3) void flash_kernel(const bfu* __restrict__ Kpc,
                                                       const bfu* __restrict__ Kcp,
                                                       const float* __restrict__ S,
                                                       float* __restrict__ out) {
    __shared__ bfu Kl_pc[PBK * 64];   // [p][c], chunk' = chunk ^ (p&7)
    __shared__ bfu Kl_cp[Cn * PBK];   // [c][p], chunk' = chunk ^ (c&15)
    __shared__ bfu Sl[QT * 64];       // [q][c], chunk' = chunk ^ (q&7)
    __shared__ bfu El[QT * PBK];      // [q][p], chunk' = chunk ^ (q&15)
    __shared__ float wredl[4][QT];

    int b  = blockIdx.x >> 7;
    int q0 = (blockIdx.x & 127) * QT;
    int t  = threadIdx.x;
    int w = t >> 6, l = t & 63, lq = l & 15, quad = l >> 4;

    const float* Sg = S   + (size_t)b * Cn * Pn;
    const bfu*   gpc = Kpc + (size_t)b * Pn * Cn;
    const bfu*   gcp = Kcp + (size_t)b * Cn * Pn;

    float4 pf_pc[4], pf_cp[4];
    // prefetch pb=0
    {
        const float4* gs = (const float4*)(gpc);
        #pragma unroll
        for (int i = 0; i < 4; ++i) pf_pc[i] = gs[i * 256 + t];
        #pragma unroll
        for (int i = 0; i < 4; ++i) {
            int idx = i * 256 + t;
            pf_cp[i] = *(const float4*)&gcp[(size_t)(idx >> 4) * Pn + (idx & 15) * 8];
        }
    }

    // Sl[q][c] = bf16(Sg[c][q0+q])  (S already scaled by log2e)
    {
        int c = t >> 2, qq = (t & 3) * 8;
        const float* sp = &Sg[(size_t)c * Pn + q0 + qq];
        float4 v0 = *(const float4*)sp;
        float4 v1 = *(const float4*)(sp + 4);
        float vv[8] = {v0.x, v0.y, v0.z, v0.w, v1.x, v1.y, v1.z, v1.w};
        int ch = c >> 3, cl = c & 7;
        #pragma unroll
        for (int i = 0; i < 8; ++i) {
            int row = qq + i;
            Sl[row * 64 + ((ch ^ (row & 7)) << 3) + cl] = f2bf(vv[i]);
        }
    }

    float4v o[2];
    o[0] = (float4v){0.f, 0.f, 0.f, 0.f};
    o[1] = (float4v){0.f, 0.f, 0.f, 0.f};
    float lacc[2] = {0.f, 0.f};

    // write K(0) tiles
    #pragma unroll
    for (int i = 0; i < 4; ++i) {
        int idx = i * 256 + t;
        int row = idx >> 3, ch = (idx & 7) ^ (row & 7);
        *(float4*)&Kl_pc[row * 64 + ch * 8] = pf_pc[i];
    }
    #pragma unroll
    for (int i = 0; i < 4; ++i) {
        int idx = i * 256 + t;
        int row = idx >> 4, ch = (idx & 15) ^ (row & 15);
        *(float4*)&Kl_cp[row * PBK + ch * 8] = pf_cp[i];
    }
    __syncthreads();

    // hoist S B-frags: B[k=c][n=q], n=lq(+16nt), k=quad*8+j (+32ks)
    short8 bs[2][2];
    #pragma unroll
    for (int nt = 0; nt < 2; ++nt)
        #pragma unroll
        for (int ks = 0; ks < 2; ++ks) {
            int row = nt * 16 + lq;
            bs[nt][ks] = *(const short8*)&Sl[row * 64 + (((ks * 4 + quad) ^ (lq & 7)) << 3)];
        }

    for (int pb = 0; pb < Pn / PBK; ++pb) {
        // ---- score GEMM: wave w owns p rows [32w, 32w+32) ----
        short8 af[2][2];
        #pragma unroll
        for (int mt = 0; mt < 2; ++mt)
            #pragma unroll
            for (int ks = 0; ks < 2; ++ks) {
                int row = w * 32 + mt * 16 + lq;
                af[mt][ks] = *(const short8*)&Kl_pc[row * 64 + (((ks * 4 + quad) ^ (lq & 7)) << 3)];
            }
        float4v sc[2][2];
        #pragma unroll
        for (int mt = 0; mt < 2; ++mt)
            #pragma unroll
            for (int nt = 0; nt < 2; ++nt) {
                float4v acc = (float4v){0.f, 0.f, 0.f, 0.f};
                acc = __builtin_amdgcn_mfma_f32_16x16x32_bf16(af[mt][0], bs[nt][0], acc, 0, 0, 0);
                acc = __builtin_amdgcn_mfma_f32_16x16x32_bf16(af[mt][1], bs[nt][1], acc, 0, 0, 0);
                sc[mt][nt] = acc;
            }

        // ---- prefetch K(pb+1) while exp/accum run ----
        if (pb < Pn / PBK - 1) {
            const float4* gs = (const float4*)(gpc + (size_t)(pb + 1) * PBK * Cn);
            #pragma unroll
            for (int i = 0; i < 4; ++i) pf_pc[i] = gs[i * 256 + t];
            #pragma unroll
            for (int i = 0; i < 4; ++i) {
                int idx = i * 256 + t;
                pf_cp[i] = *(const float4*)&gcp[(size_t)(idx >> 4) * Pn + (pb + 1) * PBK + (idx & 15) * 8];
            }
        }

        // ---- exp2 + denominator accumulation + El pack (bf16) ----
        // lane holds q = nt*16+lq, p = 32w + 16mt + 4quad + r
        #pragma unroll
        for (int nt = 0; nt < 2; ++nt) {
            int row = nt * 16 + lq;
            #pragma unroll
            for (int mt = 0; mt < 2; ++mt) {
                float e0 = __builtin_amdgcn_exp2f(sc[mt][nt][0]);
                float e1 = __builtin_amdgcn_exp2f(sc[mt][nt][1]);
                float e2 = __builtin_amdgcn_exp2f(sc[mt][nt][2]);
                float e3 = __builtin_amdgcn_exp2f(sc[mt][nt][3]);
                lacc[nt] += (e0 + e1) + (e2 + e3);
                __hip_bfloat162 h01 = __float22bfloat162_rn(make_float2(e0, e1));
                __hip_bfloat162 h23 = __float22bfloat162_rn(make_float2(e2, e3));
                uint2 pk = make_uint2(*(unsigned*)&h01, *(unsigned*)&h23);
                int col = w * 32 + mt * 16 + quad * 4;
                int ch = (col >> 3) ^ (row & 15), cl = col & 7;
                *(uint2*)&El[row * PBK + ch * 8 + cl] = pk;
            }
        }
        __syncthreads();   // El(pb) visible

        // ---- accum GEMM: wave w owns c rows [16w, 16w+16) ----
        #pragma unroll
        for (int ks = 0; ks < 4; ++ks) {
            int rowA = w * 16 + lq;
            short8 ak = *(const short8*)&Kl_cp[rowA * PBK + (((ks * 4 + quad) ^ lq) << 3)];
            #pragma unroll
            for (int nt = 0; nt < 2; ++nt) {
                int rowB = nt * 16 + lq;
                short8 bk = *(const short8*)&El[rowB * PBK + (((ks * 4 + quad) ^ lq) << 3)];
                o[nt] = __builtin_amdgcn_mfma_f32_16x16x32_bf16(ak, bk, o[nt], 0, 0, 0);
            }
        }
        __syncthreads();   // tiles free for rewrite

        if (pb < Pn / PBK - 1) {
            #pragma unroll
            for (int i = 0; i < 4; ++i) {
                int idx = i * 256 + t;
                int row = idx >> 3, ch = (idx & 7) ^ (row & 7);
                *(float4*)&Kl_pc[row * 64 + ch * 8] = pf_pc[i];
            }
            #pragma unroll
            for (int i = 0; i < 4; ++i) {
                int idx = i * 256 + t;
                int row = idx >> 4, ch = (idx & 15) ^ (row & 15);
                *(float4*)&Kl_cp[row * PBK + ch * 8] = pf_cp[i];
            }
            __syncthreads();  // K(pb+1) visible
        }
    }

    // ---- final denominator reduction + epilogue ----
    #pragma unroll
    for (int nt = 0; nt < 2; ++nt) {
        lacc[nt] += __shfl_xor(lacc[nt], 16);
        lacc[nt] += __shfl_xor(lacc[nt], 32);
    }
    if (quad == 0) { wredl[w][lq] = lacc[0]; wredl[w][16 + lq] = lacc[1]; }
    __syncthreads();
    float* og = out + (size_t)b * Cn * Pn;
    #pragma unroll
    for (int nt = 0; nt < 2; ++nt) {
        int q = nt * 16 + lq;
        float linv = 1.0f / ((wredl[0][q] + wredl[1][q]) + (wredl[2][q] + wredl[3][q]));
        #pragma unroll
        for (int r = 0; r < 4; ++r) {
            int c = w * 16 + quad * 4 + r;
            og[(size_t)c * Pn + q0 + q] = o[nt][r] * linv;
        }
    }
}

// ---------------------------------------------------------------------------
extern "C" void kernel_launch(void* const* d_in, const int* in_sizes, int n_in,
                              void* d_out, int out_size, void* d_ws, size_t ws_size,
                              hipStream_t stream) {
    const float* fg = (const float*)d_in[0];
    float* out = (float*)d_out;
    bfu*   Kpc = (bfu*)d_ws;                               // 2 MB  bf16 [B][P][C]
    bfu*   Kcp = Kpc + (size_t)Bn * Pn * Cn;               // 2 MB  bf16 [B][C][P]
    float* S   = (float*)(Kcp + (size_t)Bn * Pn * Cn);     // 4 MB  fp32 [B][C][P] (pre-scaled by log2e)

    prep_kernel <<<512, 256, 0, stream>>>(fg, Kpc, Kcp, S);
    flash_kernel<<<Bn * 128, 256, 0, stream>>>(Kpc, Kcp, S, out);
}

// Round 4
// 106.686 us; speedup vs baseline: 1.8801x; 1.8801x over previous
//
#include <hip/hip_runtime.h>
#include <hip/hip_bf16.h>
#include <math.h>

#define Bn 4
#define Cn 64
#define Pn 4096   // 64*64
#define QT 32     // q-tile per block
#define PBK 128   // p-block per flash iteration
#define NITER (Pn / PBK)
#define LOG2E 1.4426950408889634f

typedef __attribute__((ext_vector_type(8))) short short8;   // 8 bf16 = 4 VGPRs (MFMA A/B frag)
typedef __attribute__((ext_vector_type(4))) float float4v;  // MFMA C/D frag
typedef unsigned short bfu;

__device__ __forceinline__ bfu f2bf(float x) {
    unsigned u = __float_as_uint(x);
    u = (u + 0x7fffu + ((u >> 16) & 1u)) >> 16;   // RNE; inputs finite
    return (bfu)u;
}

// async global->LDS DMA, 16B per lane; LDS dest = base + lane*16 (wave-uniform base)
__device__ __forceinline__ void async_load16(const bfu* g, bfu* l) {
    __builtin_amdgcn_global_load_lds(
        (const __attribute__((address_space(1))) unsigned int*)(const void*)g,
        (__attribute__((address_space(3))) unsigned int*)(void*)l,
        16, 0, 0);
}

// ---------------------------------------------------------------------------
// Prep (fused): blocks [0,256): L2-normalize K -> bf16 Kpc [B][P][C] + Kcp [B][C][P]
//               blocks [256,512): 3x3 zero-padded box-sum * log2(e) -> S [B][C][P]
// ---------------------------------------------------------------------------
__global__ __launch_bounds__(256) void prep_kernel(const float* __restrict__ fg,
                                                   bfu* __restrict__ Kpc,
                                                   bfu* __restrict__ Kcp,
                                                   float* __restrict__ S) {
    __shared__ float shbuf[64 * 65 + 64];
    int t = threadIdx.x;
    if (blockIdx.x < 256) {
        float (*tile)[65] = (float(*)[65])shbuf;
        float* rnorm = shbuf + 64 * 65;
        int b  = blockIdx.x >> 6;
        int p0 = (blockIdx.x & 63) << 6;
        const float* src = fg + (size_t)b * Cn * Pn + p0;
        int lp = t & 63, lg = t >> 6;
        #pragma unroll
        for (int i = 0; i < 16; ++i) {
            int c = i * 4 + lg;
            tile[c][lp] = src[(size_t)c * Pn + lp];   // coalesced over p
        }
        __syncthreads();
        if (t < 64) {
            float ss = 0.f;
            #pragma unroll
            for (int c = 0; c < 64; ++c) { float v = tile[c][t]; ss += v * v; }
            rnorm[t] = 1.0f / (sqrtf(ss) + 1e-8f);
        }
        __syncthreads();
        bfu* dpc = Kpc + (size_t)b * Pn * Cn + (size_t)p0 * Cn;
        int oc = t & 63, og = t >> 6;
        #pragma unroll
        for (int i = 0; i < 16; ++i) {
            int p = i * 4 + og;
            dpc[(size_t)p * Cn + oc] = f2bf(tile[oc][p] * rnorm[p]);  // coalesced over c
        }
        bfu* dcp = Kcp + (size_t)b * Cn * Pn + p0;
        #pragma unroll
        for (int i = 0; i < 16; ++i) {
            int c = i * 4 + lg;
            dcp[(size_t)c * Pn + lp] = f2bf(tile[c][lp] * rnorm[lp]); // coalesced over p
        }
    } else {
        float (*pl)[64] = (float(*)[64])shbuf;
        int bc = blockIdx.x - 256;
        const float* src = fg + (size_t)bc * Pn;
        float*       dst = S  + (size_t)bc * Pn;
        #pragma unroll
        for (int i = 0; i < 16; ++i) {
            int idx = i * 256 + t;
            pl[idx >> 6][idx & 63] = src[idx];
        }
        __syncthreads();
        #pragma unroll
        for (int i = 0; i < 16; ++i) {
            int idx = i * 256 + t;
            int h = idx >> 6, w = idx & 63;
            float s = 0.f;
            #pragma unroll
            for (int dh = -1; dh <= 1; ++dh) {
                int hh = h + dh;
                if (hh < 0 || hh >= 64) continue;
                #pragma unroll
                for (int dw = -1; dw <= 1; ++dw) {
                    int ww = w + dw;
                    if (ww < 0 || ww >= 64) continue;
                    s += pl[hh][ww];
                }
            }
            dst[idx] = s * LOG2E;   // pre-scale so flash uses exp2 directly
        }
    }
}

// ---------------------------------------------------------------------------
// Flash (no-max softmax):  out[:,q] = K^T exp2(K·S'_q) / l_q
// grid = B*128 (QT=32); 256 threads = 4 waves; p in blocks of 128.
// K tiles double-buffered in LDS, staged via global_load_lds (16B/lane DMA);
// XOR swizzle applied on the GLOBAL source address (LDS side contiguous).
// 2 barriers per iteration.
// ---------------------------------------------------------------------------
__global__ __launch_bounds__(256, 2) void flash_kernel(const bfu* __restrict__ Kpc,
                                                       const bfu* __restrict__ Kcp,
                                                       const float* __restrict__ S,
                                                       float* __restrict__ out) {
    __shared__ bfu Kpc_l[2][PBK * 64];   // [p][c], chunk' = ch ^ (p&7)
    __shared__ bfu Kcp_l[2][Cn * PBK];   // [c][p], chunk' = ch ^ (c&15)
    __shared__ bfu Sl[QT * 64];          // [q][c], chunk' = ch ^ (q&7)
    __shared__ bfu El[QT * PBK];         // [q][p], chunk' = ch ^ (q&15)
    __shared__ float wredl[4][QT];

    int b  = blockIdx.x >> 7;
    int q0 = (blockIdx.x & 127) * QT;
    int t  = threadIdx.x;
    int w = t >> 6, l = t & 63, lq = l & 15, quad = l >> 4;

    const float* Sg  = S   + (size_t)b * Cn * Pn;
    const bfu*   gpc = Kpc + (size_t)b * Pn * Cn;
    const bfu*   gcp = Kcp + (size_t)b * Cn * Pn;

    // Sl[q][c] = bf16(Sg[c][q0+q])  (S already scaled by log2e), swizzled store
    {
        int c = t >> 2, qq = (t & 3) * 8;
        const float* sp = &Sg[(size_t)c * Pn + q0 + qq];
        float4 v0 = *(const float4*)sp;
        float4 v1 = *(const float4*)(sp + 4);
        float vv[8] = {v0.x, v0.y, v0.z, v0.w, v1.x, v1.y, v1.z, v1.w};
        int ch = c >> 3, cl = c & 7;
        #pragma unroll
        for (int i = 0; i < 8; ++i) {
            int row = qq + i;
            Sl[row * 64 + ((ch ^ (row & 7)) << 3) + cl] = f2bf(vv[i]);
        }
    }

    // stage K(0) into buffer 0 (async DMA; drained by the barrier below)
    #pragma unroll
    for (int j = 0; j < 4; ++j) {
        int ci = (w * 4 + j) * 64 + l;               // Kpc chunk index
        int row = ci >> 3, chp = ci & 7;
        async_load16(gpc + (size_t)row * Cn + ((chp ^ (row & 7)) << 3),
                     &Kpc_l[0][(w * 4 + j) * 512]);
    }
    #pragma unroll
    for (int j = 0; j < 4; ++j) {
        int ci = (w * 4 + j) * 64 + l;               // Kcp chunk index
        int c = ci >> 4, chp = ci & 15;
        async_load16(gcp + (size_t)c * Pn + ((chp ^ (c & 15)) << 3),
                     &Kcp_l[0][(w * 4 + j) * 512]);
    }
    __syncthreads();   // Sl visible + K(0) DMA drained (vmcnt(0) at barrier)

    // hoist S B-frags: B[k=c][n=q], n=lq(+16nt), k=quad*8+j (+32ks)
    short8 bs[2][2];
    #pragma unroll
    for (int nt = 0; nt < 2; ++nt)
        #pragma unroll
        for (int ks = 0; ks < 2; ++ks) {
            int row = nt * 16 + lq;
            bs[nt][ks] = *(const short8*)&Sl[row * 64 + (((ks * 4 + quad) ^ (lq & 7)) << 3)];
        }

    float4v o[2];
    o[0] = (float4v){0.f, 0.f, 0.f, 0.f};
    o[1] = (float4v){0.f, 0.f, 0.f, 0.f};
    float lacc[2] = {0.f, 0.f};

    for (int pb = 0; pb < NITER; ++pb) {
        int cur = pb & 1;

        // ---- issue DMA for K(pb+1) into the other buffer; lands during score+exp ----
        if (pb + 1 < NITER) {
            int nxt = cur ^ 1;
            const bfu* gpc_n = gpc + (size_t)(pb + 1) * PBK * Cn;
            const bfu* gcp_n = gcp + (size_t)(pb + 1) * PBK;
            #pragma unroll
            for (int j = 0; j < 4; ++j) {
                int ci = (w * 4 + j) * 64 + l;
                int row = ci >> 3, chp = ci & 7;
                async_load16(gpc_n + (size_t)row * Cn + ((chp ^ (row & 7)) << 3),
                             &Kpc_l[nxt][(w * 4 + j) * 512]);
            }
            #pragma unroll
            for (int j = 0; j < 4; ++j) {
                int ci = (w * 4 + j) * 64 + l;
                int c = ci >> 4, chp = ci & 15;
                async_load16(gcp_n + (size_t)c * Pn + ((chp ^ (c & 15)) << 3),
                             &Kcp_l[nxt][(w * 4 + j) * 512]);
            }
        }

        // ---- score GEMM: wave w owns p rows [32w, 32w+32) ----
        short8 af[2][2];
        #pragma unroll
        for (int mt = 0; mt < 2; ++mt)
            #pragma unroll
            for (int ks = 0; ks < 2; ++ks) {
                int row = w * 32 + mt * 16 + lq;
                af[mt][ks] = *(const short8*)&Kpc_l[cur][row * 64 + (((ks * 4 + quad) ^ (lq & 7)) << 3)];
            }
        float4v sc[2][2];
        #pragma unroll
        for (int mt = 0; mt < 2; ++mt)
            #pragma unroll
            for (int nt = 0; nt < 2; ++nt) {
                float4v acc = (float4v){0.f, 0.f, 0.f, 0.f};
                acc = __builtin_amdgcn_mfma_f32_16x16x32_bf16(af[mt][0], bs[nt][0], acc, 0, 0, 0);
                acc = __builtin_amdgcn_mfma_f32_16x16x32_bf16(af[mt][1], bs[nt][1], acc, 0, 0, 0);
                sc[mt][nt] = acc;
            }

        // ---- exp2 + per-lane denominator + El pack (bf16) ----
        // lane holds q = nt*16+lq, p = 32w + 16mt + 4quad + r
        #pragma unroll
        for (int nt = 0; nt < 2; ++nt) {
            int row = nt * 16 + lq;
            #pragma unroll
            for (int mt = 0; mt < 2; ++mt) {
                float e0 = __builtin_amdgcn_exp2f(sc[mt][nt][0]);
                float e1 = __builtin_amdgcn_exp2f(sc[mt][nt][1]);
                float e2 = __builtin_amdgcn_exp2f(sc[mt][nt][2]);
                float e3 = __builtin_amdgcn_exp2f(sc[mt][nt][3]);
                lacc[nt] += (e0 + e1) + (e2 + e3);
                __hip_bfloat162 h01 = __float22bfloat162_rn(make_float2(e0, e1));
                __hip_bfloat162 h23 = __float22bfloat162_rn(make_float2(e2, e3));
                uint2 pk = make_uint2(*(unsigned*)&h01, *(unsigned*)&h23);
                int col = w * 32 + mt * 16 + quad * 4;
                int ch = (col >> 3) ^ (row & 15), cl = col & 7;
                *(uint2*)&El[row * PBK + ch * 8 + cl] = pk;
            }
        }
        __syncthreads();   // El(pb) visible; K(pb+1) DMA drained here

        // ---- accum GEMM: wave w owns c rows [16w, 16w+16) ----
        #pragma unroll
        for (int ks = 0; ks < 4; ++ks) {
            int rowA = w * 16 + lq;
            short8 ak = *(const short8*)&Kcp_l[cur][rowA * PBK + (((ks * 4 + quad) ^ lq) << 3)];
            #pragma unroll
            for (int nt = 0; nt < 2; ++nt) {
                int rowB = nt * 16 + lq;
                short8 bk = *(const short8*)&El[rowB * PBK + (((ks * 4 + quad) ^ lq) << 3)];
                o[nt] = __builtin_amdgcn_mfma_f32_16x16x32_bf16(ak, bk, o[nt], 0, 0, 0);
            }
        }
        __syncthreads();   // El free for rewrite next iter
    }

    // ---- final denominator reduction + epilogue ----
    #pragma unroll
    for (int nt = 0; nt < 2; ++nt) {
        lacc[nt] += __shfl_xor(lacc[nt], 16);
        lacc[nt] += __shfl_xor(lacc[nt], 32);
    }
    if (quad == 0) { wredl[w][lq] = lacc[0]; wredl[w][16 + lq] = lacc[1]; }
    __syncthreads();
    float* og = out + (size_t)b * Cn * Pn;
    #pragma unroll
    for (int nt = 0; nt < 2; ++nt) {
        int q = nt * 16 + lq;
        float linv = 1.0f / ((wredl[0][q] + wredl[1][q]) + (wredl[2][q] + wredl[3][q]));
        #pragma unroll
        for (int r = 0; r < 4; ++r) {
            int c = w * 16 + quad * 4 + r;
            og[(size_t)c * Pn + q0 + q] = o[nt][r] * linv;
        }
    }
}

// ---------------------------------------------------------------------------
extern "C" void kernel_launch(void* const* d_in, const int* in_sizes, int n_in,
                              void* d_out, int out_size, void* d_ws, size_t ws_size,
                              hipStream_t stream) {
    const float* fg = (const float*)d_in[0];
    float* out = (float*)d_out;
    bfu*   Kpc = (bfu*)d_ws;                               // 2 MB  bf16 [B][P][C]
    bfu*   Kcp = Kpc + (size_t)Bn * Pn * Cn;               // 2 MB  bf16 [B][C][P]
    float* S   = (float*)(Kcp + (size_t)Bn * Pn * Cn);     // 4 MB  fp32 [B][C][P] (pre-scaled by log2e)

    prep_kernel <<<512, 256, 0, stream>>>(fg, Kpc, Kcp, S);
    flash_kernel<<<Bn * 128, 256, 0, stream>>>(Kpc, Kcp, S, out);
}